// Round 7
// baseline (403.327 us; speedup 1.0000x reference)
//
#include <hip/hip_runtime.h>
#include <hip/hip_bf16.h>
#include <stdint.h>

#define B_ 2
#define S_ 2048
#define D_ 2048
#define H_ 8
#define DK_ 256
#define SCALE_ 0.0625f
#define NEG_ -1e9f

typedef __hip_bfloat16 bf16;
typedef __attribute__((ext_vector_type(4))) float f32x4;
typedef __attribute__((ext_vector_type(8))) short bf16x8;
typedef unsigned int u32;

__device__ inline void gload_lds16(const void* g, void* l) {
  __builtin_amdgcn_global_load_lds(
      (const __attribute__((address_space(1))) u32*)g,
      (__attribute__((address_space(3))) u32*)l, 16, 0, 0);
}

// ---------------- fused fp32 -> bf16 convert (x, Wq, Wk in one launch) ----------------
__global__ void cvt_all_kernel(const float* __restrict__ x, bf16* __restrict__ xo,
                               const float* __restrict__ wq, bf16* __restrict__ wqo,
                               const float* __restrict__ wk, bf16* __restrict__ wko,
                               int nX4, int nW4) {
  int i = blockIdx.x * 256 + threadIdx.x;
  const float* in; bf16* out; int idx;
  if (i < nX4) { in = x; out = xo; idx = i; }
  else if (i < nX4 + nW4) { in = wq; out = wqo; idx = i - nX4; }
  else { in = wk; out = wko; idx = i - nX4 - nW4; }
  float4 v = ((const float4*)in)[idx];
  ushort4 o;
  o.x = __builtin_bit_cast(unsigned short, __float2bfloat16(v.x));
  o.y = __builtin_bit_cast(unsigned short, __float2bfloat16(v.y));
  o.z = __builtin_bit_cast(unsigned short, __float2bfloat16(v.z));
  o.w = __builtin_bit_cast(unsigned short, __float2bfloat16(v.w));
  ((ushort4*)out)[idx] = o;
}

// ---------------- fused Q/K projection GEMM (m97 structure) ----------------
// C = A[M,K] @ W[N,K]^T + bias, stored bf16 HEAD-MAJOR: C[b,h,s,dk].
__global__ __launch_bounds__(256, 2) void gemm_qk(
    const bf16* __restrict__ A,
    const bf16* __restrict__ W0, const float* __restrict__ b0, bf16* __restrict__ C0,
    const bf16* __restrict__ W1, const float* __restrict__ b1, bf16* __restrict__ C1) {
  const int Kd = D_;
  const bf16* Bm = blockIdx.z ? W1 : W0;
  const float* bias = blockIdx.z ? b1 : b0;
  bf16* C = blockIdx.z ? C1 : C0;

  __shared__ bf16 As[128 * 64];
  __shared__ bf16 Bs[128 * 64];
  const int tid = threadIdx.x;
  const int lane = tid & 63;
  const int w = tid >> 6;
  const int wr = w >> 1, wc = w & 1;
  const int bm = blockIdx.y, bn = blockIdx.x;

  f32x4 acc[4][4] = {};
  const int l8r = lane >> 3;        // 0..7 row within 8-row chunk
  const int l8c = (lane & 7) * 8;   // k element offset (8 bf16 = 16B)

  for (int kt = 0; kt < Kd; kt += 64) {
#pragma unroll
    for (int cc = 0; cc < 4; ++cc) {
      int chunk = w * 4 + cc;                       // 0..15
      int rowa = bm * 128 + chunk * 8 + l8r;
      gload_lds16(A + (size_t)rowa * Kd + kt + l8c, (char*)As + chunk * 1024);
      int rowb = bn * 128 + chunk * 8 + l8r;
      gload_lds16(Bm + (size_t)rowb * Kd + kt + l8c, (char*)Bs + chunk * 1024);
    }
    __syncthreads();
#pragma unroll
    for (int kk = 0; kk < 2; ++kk) {
      const int kloc = kk * 32 + (lane >> 4) * 8;
      bf16x8 af[4], bfr[4];
#pragma unroll
      for (int mi = 0; mi < 4; ++mi) {
        int row = wr * 64 + mi * 16 + (lane & 15);
        af[mi] = *(const bf16x8*)&As[row * 64 + kloc];
      }
#pragma unroll
      for (int ni = 0; ni < 4; ++ni) {
        int row = wc * 64 + ni * 16 + (lane & 15);
        bfr[ni] = *(const bf16x8*)&Bs[row * 64 + kloc];
      }
#pragma unroll
      for (int mi = 0; mi < 4; ++mi)
#pragma unroll
        for (int ni = 0; ni < 4; ++ni)
          acc[mi][ni] = __builtin_amdgcn_mfma_f32_16x16x32_bf16(af[mi], bfr[ni], acc[mi][ni], 0, 0, 0);
    }
    __syncthreads();
  }
  // epilogue: C layout col=lane&15, row=(lane>>4)*4+r ; store head-major
#pragma unroll
  for (int ni = 0; ni < 4; ++ni) {
    int col = bn * 128 + wc * 64 + ni * 16 + (lane & 15);
    int h = col >> 8, dk = col & 255;
    float bb = bias[col];
#pragma unroll
    for (int mi = 0; mi < 4; ++mi) {
      int rbase = bm * 128 + wr * 64 + mi * 16 + (lane >> 4) * 4;
#pragma unroll
      for (int r = 0; r < 4; ++r) {
        int row = rbase + r;
        int b = row >> 11, s = row & 2047;
        C[(((size_t)b * H_ + h) * S_ + s) * DK_ + dk] = __float2bfloat16(acc[mi][ni][r] + bb);
      }
    }
  }
}

// ---------------- score kernel v4: no LDS staging, K from L2, j-split x2 ----------------
// score[bh,i] = sum_j lrelu(q_i.k_j)*Wa[j]; head-major Q/K [bh,S,DK].
// grid (16 bh, 32 it, 2 jh) = 1024 blocks -> 4/CU, 16 waves/CU.
// linear id % 8 == bh % 8 (gridDim.x=16) -> per-head XCD L2 affinity.
// 256 thr = 4 waves 2x2: wr -> 32 i-rows (mi=2), wc -> 64 j per 128-j pass.
__global__ __launch_bounds__(256, 4) void score_kernel(
    const bf16* __restrict__ Qh, const bf16* __restrict__ Kh,
    const float* __restrict__ Wa, float* __restrict__ score) {
  __shared__ float sred[2][64];
  const int tid = threadIdx.x, lane = tid & 63, w = tid >> 6;
  const int wr = w >> 1, wc = w & 1;
  const int bh = blockIdx.x;
  const int it = blockIdx.y;
  const int jh = blockIdx.z;

  const bf16* Qbase = Qh + (size_t)bh * S_ * DK_;
  const bf16* Kbase = Kh + (size_t)bh * S_ * DK_ + (size_t)jh * 1024 * DK_;
  const float* Wab = Wa + jh * 1024;

  // Q fragments in registers (A-operand: row=lane&15, k=(lane>>4)*8 + kc*32)
  bf16x8 qf[2][8];
#pragma unroll
  for (int mi = 0; mi < 2; ++mi) {
    int row = it * 64 + wr * 32 + mi * 16 + (lane & 15);
    const bf16* qp = Qbase + (size_t)row * DK_ + ((lane >> 4) * 8);
#pragma unroll
    for (int kc = 0; kc < 8; ++kc) qf[mi][kc] = *(const bf16x8*)(qp + kc * 32);
  }

  float psum[2][4] = {};
  const int koff = (lane >> 4) * 8;

  for (int jt = 0; jt < 8; ++jt) {
#pragma unroll 2
    for (int nj = 0; nj < 4; ++nj) {
      int jrow = jt * 128 + wc * 64 + nj * 16 + (lane & 15);
      const bf16* kp = Kbase + (size_t)jrow * DK_ + koff;
      bf16x8 bfr[8];
#pragma unroll
      for (int kc = 0; kc < 8; ++kc) bfr[kc] = *(const bf16x8*)(kp + kc * 32);
      f32x4 cf[2] = {};
#pragma unroll
      for (int kc = 0; kc < 8; ++kc)
#pragma unroll
        for (int mi = 0; mi < 2; ++mi)
          cf[mi] = __builtin_amdgcn_mfma_f32_16x16x32_bf16(qf[mi][kc], bfr[kc], cf[mi], 0, 0, 0);
      float wa = Wab[jrow];
#pragma unroll
      for (int mi = 0; mi < 2; ++mi)
#pragma unroll
        for (int r = 0; r < 4; ++r) {
          float v = cf[mi][r];
          v = (v > 0.f) ? v : 0.1f * v;   // leaky_relu 0.1
          psum[mi][r] += v * wa;
        }
    }
  }
  // lanes within each 16-group hold 16 distinct j columns -> reduce
#pragma unroll
  for (int mi = 0; mi < 2; ++mi)
#pragma unroll
    for (int r = 0; r < 4; ++r) {
      float v = psum[mi][r];
      v += __shfl_xor(v, 1); v += __shfl_xor(v, 2);
      v += __shfl_xor(v, 4); v += __shfl_xor(v, 8);
      if ((lane & 15) == 0) {
        int lrow = wr * 32 + mi * 16 + ((lane >> 4) * 4) + r;  // 0..63
        sred[wc][lrow] = v;   // each wc-wave covered half the j columns
      }
    }
  __syncthreads();
  if (tid < 64)
    atomicAdd(&score[(size_t)bh * S_ + it * 64 + tid], sred[0][tid] + sred[1][tid]);
}

// ---------------- masked scaled softmax over tokens ----------------
__global__ __launch_bounds__(256) void softmax_kernel(
    const float* __restrict__ score, const int* __restrict__ xmask,
    const float* __restrict__ ba, float* __restrict__ attn) {
  const int bh = blockIdx.x, tid = threadIdx.x;
  const int lane = tid & 63, w = tid >> 6;
  __shared__ float redm[4], reds[4];
  const float ba0 = ba[0];
  float loc[8];
  float mx = -3.4e38f;
#pragma unroll
  for (int t = 0; t < 8; ++t) {
    int i = t * 256 + tid;
    float s = SCALE_ * (score[(size_t)bh * S_ + i] + ba0);
    if (xmask[i] != 0) s = NEG_;
    loc[t] = s;
    mx = fmaxf(mx, s);
  }
  for (int m = 1; m < 64; m <<= 1) mx = fmaxf(mx, __shfl_xor(mx, m));
  if (lane == 0) redm[w] = mx;
  __syncthreads();
  mx = fmaxf(fmaxf(redm[0], redm[1]), fmaxf(redm[2], redm[3]));
  float sum = 0.f;
#pragma unroll
  for (int t = 0; t < 8; ++t) {
    loc[t] = expf(loc[t] - mx);
    sum += loc[t];
  }
  for (int m = 1; m < 64; m <<= 1) sum += __shfl_xor(sum, m);
  if (lane == 0) reds[w] = sum;
  __syncthreads();
  sum = reds[0] + reds[1] + reds[2] + reds[3];
  const float inv = 1.f / sum;
#pragma unroll
  for (int t = 0; t < 8; ++t) attn[(size_t)bh * S_ + t * 256 + tid] = loc[t] * inv;
}

// ---------------- xbar partials: part[sblk][b][h][c] = sum_{s in blk} attn*x ----------------
// grid (2 cblk, 64 sblk, B); no atomics, direct float4 stores.
__global__ __launch_bounds__(256) void xbar_part_kernel(
    const float* __restrict__ x, const float* __restrict__ attn, float* __restrict__ part) {
  const int cblk = blockIdx.x, sblk = blockIdx.y, b = blockIdx.z;
  const int tid = threadIdx.x;
  const int c = cblk * 1024 + tid * 4;
  __shared__ float at_s[8][32];
  for (int i = tid; i < 8 * 32; i += 256) {
    int h = i >> 5, s = i & 31;
    at_s[h][s] = attn[((size_t)b * H_ + h) * S_ + sblk * 32 + s];
  }
  __syncthreads();
  float acc[8][4] = {};
  const float* xp = x + ((size_t)b * S_ + sblk * 32) * D_ + c;
#pragma unroll 8
  for (int s = 0; s < 32; ++s) {
    float4 xv = *(const float4*)(xp + (size_t)s * D_);
#pragma unroll
    for (int h = 0; h < 8; ++h) {
      float a = at_s[h][s];
      acc[h][0] += a * xv.x; acc[h][1] += a * xv.y;
      acc[h][2] += a * xv.z; acc[h][3] += a * xv.w;
    }
  }
  float* pp = part + (((size_t)sblk * B_ + b) * H_) * D_ + c;
#pragma unroll
  for (int h = 0; h < 8; ++h)
    *(float4*)(pp + (size_t)h * D_) = *(const float4*)&acc[h][0];
}

// ---------------- xbar[b][h][c] = sum_sblk part[sblk][b][h][c] ----------------
__global__ __launch_bounds__(256) void xbar_reduce_kernel(
    const float* __restrict__ part, float* __restrict__ xbar) {
  const int idx = blockIdx.x * 256 + threadIdx.x;  // [0, B*H*D)
  float s = 0.f;
#pragma unroll 8
  for (int sb = 0; sb < 64; ++sb)
    s += part[(size_t)sb * (B_ * H_ * D_) + idx];
  xbar[idx] = s;
}

// ---------------- pooled[b,dv] = xbar[b,h(dv),:].Wv[dv,:] + bv[dv] ----------------
__global__ __launch_bounds__(256) void pooled_kernel(
    const float* __restrict__ xbar, const float* __restrict__ Wv,
    const float* __restrict__ bv, float* __restrict__ pooled) {
  const int lane = threadIdx.x & 63;
  const int dv = blockIdx.x * 4 + (threadIdx.x >> 6);
  const int h = dv >> 8;  // dv / DK_
  const float* wrow = Wv + (size_t)dv * D_;
  const float* x0 = xbar + (size_t)h * D_;
  const float* x1 = xbar + (size_t)(H_ + h) * D_;
  float a0 = 0.f, a1 = 0.f;
  for (int c = lane; c < D_; c += 64) {
    float wv = wrow[c];
    a0 += wv * x0[c];
    a1 += wv * x1[c];
  }
  for (int m = 1; m < 64; m <<= 1) { a0 += __shfl_xor(a0, m); a1 += __shfl_xor(a1, m); }
  if (lane == 0) {
    float bb = bv[dv];
    pooled[dv] = a0 + bb;
    pooled[D_ + dv] = a1 + bb;
  }
}

// ---------------- out[b,n] = tanh(pooled[b,:].Wp[n,:] + bp[n]) ----------------
__global__ __launch_bounds__(256) void final_kernel(
    const float* __restrict__ pooled, const float* __restrict__ Wp,
    const float* __restrict__ bp, float* __restrict__ out) {
  const int lane = threadIdx.x & 63;
  const int n = blockIdx.x * 4 + (threadIdx.x >> 6);
  const float* wrow = Wp + (size_t)n * D_;
  float a0 = 0.f, a1 = 0.f;
  for (int c = lane; c < D_; c += 64) {
    float wv = wrow[c];
    a0 += wv * pooled[c];
    a1 += wv * pooled[D_ + c];
  }
  for (int m = 1; m < 64; m <<= 1) { a0 += __shfl_xor(a0, m); a1 += __shfl_xor(a1, m); }
  if (lane == 0) {
    float bb = bp[n];
    out[n] = tanhf(a0 + bb);
    out[D_ + n] = tanhf(a1 + bb);
  }
}

extern "C" void kernel_launch(void* const* d_in, const int* in_sizes, int n_in,
                              void* d_out, int out_size, void* d_ws, size_t ws_size,
                              hipStream_t stream) {
  const float* x = (const float*)d_in[0];
  const int* xmask = (const int*)d_in[1];
  const float* Wq = (const float*)d_in[2];
  const float* bq = (const float*)d_in[3];
  const float* Wk = (const float*)d_in[4];
  const float* bk = (const float*)d_in[5];
  const float* Wv = (const float*)d_in[6];
  const float* bv = (const float*)d_in[7];
  const float* Wa = (const float*)d_in[8];
  const float* ba = (const float*)d_in[9];
  const float* Wp = (const float*)d_in[10];
  const float* bp = (const float*)d_in[11];
  float* out = (float*)d_out;

  char* ws = (char*)d_ws;
  bf16* Xb = (bf16*)ws;    ws += (size_t)B_ * S_ * D_ * 2;
  bf16* Wqb = (bf16*)ws;   ws += (size_t)D_ * D_ * 2;
  bf16* Wkb = (bf16*)ws;   ws += (size_t)D_ * D_ * 2;
  bf16* Qb = (bf16*)ws;    ws += (size_t)B_ * S_ * D_ * 2;   // head-major [bh,S,DK]
  bf16* Kbf = (bf16*)ws;   ws += (size_t)B_ * S_ * D_ * 2;   // head-major [bh,S,DK]
  float* score = (float*)ws;  ws += (size_t)B_ * H_ * S_ * 4;
  float* attn = (float*)ws;   ws += (size_t)B_ * H_ * S_ * 4;
  float* xbar = (float*)ws;   ws += (size_t)B_ * H_ * D_ * 4;
  float* pooled = (float*)ws; ws += (size_t)B_ * D_ * 4;
  // part overlays Wqb/Wkb (16 MB, dead after gemm_qk); needs 64*B*H*D*4 = 8.4 MB
  float* part = (float*)Wqb;

  const int nX4 = B_ * S_ * D_ / 4, nW4 = D_ * D_ / 4;
  cvt_all_kernel<<<(nX4 + 2 * nW4) / 256, 256, 0, stream>>>(
      x, Xb, Wq, Wqb, Wk, Wkb, nX4, nW4);

  gemm_qk<<<dim3(D_ / 128, B_ * S_ / 128, 2), 256, 0, stream>>>(
      Xb, Wqb, bq, Qb, Wkb, bk, Kbf);

  hipMemsetAsync(score, 0, (size_t)B_ * H_ * S_ * 4, stream);
  score_kernel<<<dim3(B_ * H_, S_ / 64, 2), 256, 0, stream>>>(Qb, Kbf, Wa, score);

  softmax_kernel<<<B_ * H_, 256, 0, stream>>>(score, xmask, ba, attn);

  xbar_part_kernel<<<dim3(2, 64, B_), 256, 0, stream>>>(x, attn, part);
  xbar_reduce_kernel<<<B_ * H_ * D_ / 256, 256, 0, stream>>>(part, xbar);

  pooled_kernel<<<D_ / 4, 256, 0, stream>>>(xbar, Wv, bv, pooled);
  final_kernel<<<D_ / 4, 256, 0, stream>>>(pooled, Wp, bp, out);
}

// Round 8
// 343.324 us; speedup vs baseline: 1.1748x; 1.1748x over previous
//
#include <hip/hip_runtime.h>
#include <hip/hip_bf16.h>
#include <stdint.h>

#define B_ 2
#define S_ 2048
#define D_ 2048
#define H_ 8
#define DK_ 256
#define SCALE_ 0.0625f
#define NEG_ -1e9f

typedef __hip_bfloat16 bf16;
typedef __attribute__((ext_vector_type(4))) float f32x4;
typedef __attribute__((ext_vector_type(8))) short bf16x8;
typedef unsigned int u32;

__device__ inline void gload_lds16(const void* g, void* l) {
  __builtin_amdgcn_global_load_lds(
      (const __attribute__((address_space(1))) u32*)g,
      (__attribute__((address_space(3))) u32*)l, 16, 0, 0);
}

// ---------------- fused fp32 -> bf16 convert (x, Wq, Wk in one launch) ----------------
__global__ void cvt_all_kernel(const float* __restrict__ x, bf16* __restrict__ xo,
                               const float* __restrict__ wq, bf16* __restrict__ wqo,
                               const float* __restrict__ wk, bf16* __restrict__ wko,
                               int nX4, int nW4) {
  int i = blockIdx.x * 256 + threadIdx.x;
  const float* in; bf16* out; int idx;
  if (i < nX4) { in = x; out = xo; idx = i; }
  else if (i < nX4 + nW4) { in = wq; out = wqo; idx = i - nX4; }
  else { in = wk; out = wko; idx = i - nX4 - nW4; }
  float4 v = ((const float4*)in)[idx];
  ushort4 o;
  o.x = __builtin_bit_cast(unsigned short, __float2bfloat16(v.x));
  o.y = __builtin_bit_cast(unsigned short, __float2bfloat16(v.y));
  o.z = __builtin_bit_cast(unsigned short, __float2bfloat16(v.z));
  o.w = __builtin_bit_cast(unsigned short, __float2bfloat16(v.w));
  ((ushort4*)out)[idx] = o;
}

// ---------------- fused Q/K projection GEMM (m97 structure) ----------------
// C = A[M,K] @ W[N,K]^T + bias, stored bf16 HEAD-MAJOR: C[b,h,s,dk].
__global__ __launch_bounds__(256, 2) void gemm_qk(
    const bf16* __restrict__ A,
    const bf16* __restrict__ W0, const float* __restrict__ b0, bf16* __restrict__ C0,
    const bf16* __restrict__ W1, const float* __restrict__ b1, bf16* __restrict__ C1) {
  const int Kd = D_;
  const bf16* Bm = blockIdx.z ? W1 : W0;
  const float* bias = blockIdx.z ? b1 : b0;
  bf16* C = blockIdx.z ? C1 : C0;

  __shared__ bf16 As[128 * 64];
  __shared__ bf16 Bs[128 * 64];
  const int tid = threadIdx.x;
  const int lane = tid & 63;
  const int w = tid >> 6;
  const int wr = w >> 1, wc = w & 1;
  const int bm = blockIdx.y, bn = blockIdx.x;

  f32x4 acc[4][4] = {};
  const int l8r = lane >> 3;        // 0..7 row within 8-row chunk
  const int l8c = (lane & 7) * 8;   // k element offset (8 bf16 = 16B)

  for (int kt = 0; kt < Kd; kt += 64) {
#pragma unroll
    for (int cc = 0; cc < 4; ++cc) {
      int chunk = w * 4 + cc;                       // 0..15
      int rowa = bm * 128 + chunk * 8 + l8r;
      gload_lds16(A + (size_t)rowa * Kd + kt + l8c, (char*)As + chunk * 1024);
      int rowb = bn * 128 + chunk * 8 + l8r;
      gload_lds16(Bm + (size_t)rowb * Kd + kt + l8c, (char*)Bs + chunk * 1024);
    }
    __syncthreads();
#pragma unroll
    for (int kk = 0; kk < 2; ++kk) {
      const int kloc = kk * 32 + (lane >> 4) * 8;
      bf16x8 af[4], bfr[4];
#pragma unroll
      for (int mi = 0; mi < 4; ++mi) {
        int row = wr * 64 + mi * 16 + (lane & 15);
        af[mi] = *(const bf16x8*)&As[row * 64 + kloc];
      }
#pragma unroll
      for (int ni = 0; ni < 4; ++ni) {
        int row = wc * 64 + ni * 16 + (lane & 15);
        bfr[ni] = *(const bf16x8*)&Bs[row * 64 + kloc];
      }
#pragma unroll
      for (int mi = 0; mi < 4; ++mi)
#pragma unroll
        for (int ni = 0; ni < 4; ++ni)
          acc[mi][ni] = __builtin_amdgcn_mfma_f32_16x16x32_bf16(af[mi], bfr[ni], acc[mi][ni], 0, 0, 0);
    }
    __syncthreads();
  }
  // epilogue: C layout col=lane&15, row=(lane>>4)*4+r ; store head-major
#pragma unroll
  for (int ni = 0; ni < 4; ++ni) {
    int col = bn * 128 + wc * 64 + ni * 16 + (lane & 15);
    int h = col >> 8, dk = col & 255;
    float bb = bias[col];
#pragma unroll
    for (int mi = 0; mi < 4; ++mi) {
      int rbase = bm * 128 + wr * 64 + mi * 16 + (lane >> 4) * 4;
#pragma unroll
      for (int r = 0; r < 4; ++r) {
        int row = rbase + r;
        int b = row >> 11, s = row & 2047;
        C[(((size_t)b * H_ + h) * S_ + s) * DK_ + dk] = __float2bfloat16(acc[mi][ni][r] + bb);
      }
    }
  }
}

// ---------------- score kernel v5: m97-style GEMM tile with fused lrelu*Wa epilogue ----
// score[bh,i] += sum_{j in tile} lrelu(q_i.k_j)*Wa[j]; head-major Q/K [bh,S,DK].
// grid (16 bh, 16 bm, 16 bn): linear id % 8 == bh % 8 -> per-head XCD L2 affinity.
// Identical staging/MFMA structure to gemm_qk (contiguous global_load_lds, 4 k-steps).
__global__ __launch_bounds__(256, 2) void score_kernel(
    const bf16* __restrict__ Qh, const bf16* __restrict__ Kh,
    const float* __restrict__ Wa, float* __restrict__ score) {
  __shared__ bf16 Qs[128 * 64];
  __shared__ bf16 Ks[128 * 64];
  __shared__ float sred[2][128];
  const int tid = threadIdx.x;
  const int lane = tid & 63;
  const int w = tid >> 6;
  const int wr = w >> 1, wc = w & 1;
  const int bh = blockIdx.x, bm = blockIdx.y, bn = blockIdx.z;

  const bf16* Qbase = Qh + (size_t)bh * S_ * DK_;
  const bf16* Kbase = Kh + (size_t)bh * S_ * DK_;

  f32x4 acc[4][4] = {};
  const int l8r = lane >> 3;
  const int l8c = (lane & 7) * 8;

  for (int kt = 0; kt < DK_; kt += 64) {
#pragma unroll
    for (int cc = 0; cc < 4; ++cc) {
      int chunk = w * 4 + cc;                       // 0..15
      int rowa = bm * 128 + chunk * 8 + l8r;
      gload_lds16(Qbase + (size_t)rowa * DK_ + kt + l8c, (char*)Qs + chunk * 1024);
      int rowb = bn * 128 + chunk * 8 + l8r;
      gload_lds16(Kbase + (size_t)rowb * DK_ + kt + l8c, (char*)Ks + chunk * 1024);
    }
    __syncthreads();
#pragma unroll
    for (int kk = 0; kk < 2; ++kk) {
      const int kloc = kk * 32 + (lane >> 4) * 8;
      bf16x8 af[4], bfr[4];
#pragma unroll
      for (int mi = 0; mi < 4; ++mi) {
        int row = wr * 64 + mi * 16 + (lane & 15);
        af[mi] = *(const bf16x8*)&Qs[row * 64 + kloc];
      }
#pragma unroll
      for (int ni = 0; ni < 4; ++ni) {
        int row = wc * 64 + ni * 16 + (lane & 15);
        bfr[ni] = *(const bf16x8*)&Ks[row * 64 + kloc];
      }
#pragma unroll
      for (int mi = 0; mi < 4; ++mi)
#pragma unroll
        for (int ni = 0; ni < 4; ++ni)
          acc[mi][ni] = __builtin_amdgcn_mfma_f32_16x16x32_bf16(af[mi], bfr[ni], acc[mi][ni], 0, 0, 0);
    }
    __syncthreads();
  }
  // epilogue: lane holds cols (ni, lane&15), rows (mi, (lane>>4)*4+r)
  float wa_v[4];
#pragma unroll
  for (int ni = 0; ni < 4; ++ni)
    wa_v[ni] = Wa[bn * 128 + wc * 64 + ni * 16 + (lane & 15)];
  float psum[4][4] = {};   // [mi][r]
#pragma unroll
  for (int mi = 0; mi < 4; ++mi)
#pragma unroll
    for (int ni = 0; ni < 4; ++ni)
#pragma unroll
      for (int r = 0; r < 4; ++r) {
        float v = acc[mi][ni][r];
        v = (v > 0.f) ? v : 0.1f * v;   // leaky_relu 0.1
        psum[mi][r] += v * wa_v[ni];
      }
  // reduce the 16 col-lanes within each 16-lane group
#pragma unroll
  for (int mi = 0; mi < 4; ++mi)
#pragma unroll
    for (int r = 0; r < 4; ++r) {
      float v = psum[mi][r];
      v += __shfl_xor(v, 1); v += __shfl_xor(v, 2);
      v += __shfl_xor(v, 4); v += __shfl_xor(v, 8);
      if ((lane & 15) == 0) {
        int lrow = wr * 64 + mi * 16 + ((lane >> 4) * 4) + r;  // 0..127
        sred[wc][lrow] = v;   // each wc-wave covered half the j columns
      }
    }
  __syncthreads();
  if (tid < 128)
    atomicAdd(&score[(size_t)bh * S_ + bm * 128 + tid], sred[0][tid] + sred[1][tid]);
}

// ---------------- masked scaled softmax over tokens ----------------
__global__ __launch_bounds__(256) void softmax_kernel(
    const float* __restrict__ score, const int* __restrict__ xmask,
    const float* __restrict__ ba, float* __restrict__ attn) {
  const int bh = blockIdx.x, tid = threadIdx.x;
  const int lane = tid & 63, w = tid >> 6;
  __shared__ float redm[4], reds[4];
  const float ba0 = ba[0];
  float loc[8];
  float mx = -3.4e38f;
#pragma unroll
  for (int t = 0; t < 8; ++t) {
    int i = t * 256 + tid;
    float s = SCALE_ * (score[(size_t)bh * S_ + i] + ba0);
    if (xmask[i] != 0) s = NEG_;
    loc[t] = s;
    mx = fmaxf(mx, s);
  }
  for (int m = 1; m < 64; m <<= 1) mx = fmaxf(mx, __shfl_xor(mx, m));
  if (lane == 0) redm[w] = mx;
  __syncthreads();
  mx = fmaxf(fmaxf(redm[0], redm[1]), fmaxf(redm[2], redm[3]));
  float sum = 0.f;
#pragma unroll
  for (int t = 0; t < 8; ++t) {
    loc[t] = expf(loc[t] - mx);
    sum += loc[t];
  }
  for (int m = 1; m < 64; m <<= 1) sum += __shfl_xor(sum, m);
  if (lane == 0) reds[w] = sum;
  __syncthreads();
  sum = reds[0] + reds[1] + reds[2] + reds[3];
  const float inv = 1.f / sum;
#pragma unroll
  for (int t = 0; t < 8; ++t) attn[(size_t)bh * S_ + t * 256 + tid] = loc[t] * inv;
}

// ---------------- xbar partials: part[sblk][b][h][c] = sum_{s in blk} attn*x ----------------
// grid (2 cblk, 64 sblk, B); no atomics, direct float4 stores.
__global__ __launch_bounds__(256) void xbar_part_kernel(
    const float* __restrict__ x, const float* __restrict__ attn, float* __restrict__ part) {
  const int cblk = blockIdx.x, sblk = blockIdx.y, b = blockIdx.z;
  const int tid = threadIdx.x;
  const int c = cblk * 1024 + tid * 4;
  __shared__ float at_s[8][32];
  for (int i = tid; i < 8 * 32; i += 256) {
    int h = i >> 5, s = i & 31;
    at_s[h][s] = attn[((size_t)b * H_ + h) * S_ + sblk * 32 + s];
  }
  __syncthreads();
  float acc[8][4] = {};
  const float* xp = x + ((size_t)b * S_ + sblk * 32) * D_ + c;
#pragma unroll 8
  for (int s = 0; s < 32; ++s) {
    float4 xv = *(const float4*)(xp + (size_t)s * D_);
#pragma unroll
    for (int h = 0; h < 8; ++h) {
      float a = at_s[h][s];
      acc[h][0] += a * xv.x; acc[h][1] += a * xv.y;
      acc[h][2] += a * xv.z; acc[h][3] += a * xv.w;
    }
  }
  float* pp = part + (((size_t)sblk * B_ + b) * H_) * D_ + c;
#pragma unroll
  for (int h = 0; h < 8; ++h)
    *(float4*)(pp + (size_t)h * D_) = *(const float4*)&acc[h][0];
}

// ---------------- xbar[b][h][c] = sum_sblk part[sblk][b][h][c] ----------------
__global__ __launch_bounds__(256) void xbar_reduce_kernel(
    const float* __restrict__ part, float* __restrict__ xbar) {
  const int idx = blockIdx.x * 256 + threadIdx.x;  // [0, B*H*D)
  float s = 0.f;
#pragma unroll 8
  for (int sb = 0; sb < 64; ++sb)
    s += part[(size_t)sb * (B_ * H_ * D_) + idx];
  xbar[idx] = s;
}

// ---------------- pooled[b,dv] = xbar[b,h(dv),:].Wv[dv,:] + bv[dv] ----------------
__global__ __launch_bounds__(256) void pooled_kernel(
    const float* __restrict__ xbar, const float* __restrict__ Wv,
    const float* __restrict__ bv, float* __restrict__ pooled) {
  const int lane = threadIdx.x & 63;
  const int dv = blockIdx.x * 4 + (threadIdx.x >> 6);
  const int h = dv >> 8;  // dv / DK_
  const float* wrow = Wv + (size_t)dv * D_;
  const float* x0 = xbar + (size_t)h * D_;
  const float* x1 = xbar + (size_t)(H_ + h) * D_;
  float a0 = 0.f, a1 = 0.f;
  for (int c = lane; c < D_; c += 64) {
    float wv = wrow[c];
    a0 += wv * x0[c];
    a1 += wv * x1[c];
  }
  for (int m = 1; m < 64; m <<= 1) { a0 += __shfl_xor(a0, m); a1 += __shfl_xor(a1, m); }
  if (lane == 0) {
    float bb = bv[dv];
    pooled[dv] = a0 + bb;
    pooled[D_ + dv] = a1 + bb;
  }
}

// ---------------- out[b,n] = tanh(pooled[b,:].Wp[n,:] + bp[n]) ----------------
__global__ __launch_bounds__(256) void final_kernel(
    const float* __restrict__ pooled, const float* __restrict__ Wp,
    const float* __restrict__ bp, float* __restrict__ out) {
  const int lane = threadIdx.x & 63;
  const int n = blockIdx.x * 4 + (threadIdx.x >> 6);
  const float* wrow = Wp + (size_t)n * D_;
  float a0 = 0.f, a1 = 0.f;
  for (int c = lane; c < D_; c += 64) {
    float wv = wrow[c];
    a0 += wv * pooled[c];
    a1 += wv * pooled[D_ + c];
  }
  for (int m = 1; m < 64; m <<= 1) { a0 += __shfl_xor(a0, m); a1 += __shfl_xor(a1, m); }
  if (lane == 0) {
    float bb = bp[n];
    out[n] = tanhf(a0 + bb);
    out[D_ + n] = tanhf(a1 + bb);
  }
}

extern "C" void kernel_launch(void* const* d_in, const int* in_sizes, int n_in,
                              void* d_out, int out_size, void* d_ws, size_t ws_size,
                              hipStream_t stream) {
  const float* x = (const float*)d_in[0];
  const int* xmask = (const int*)d_in[1];
  const float* Wq = (const float*)d_in[2];
  const float* bq = (const float*)d_in[3];
  const float* Wk = (const float*)d_in[4];
  const float* bk = (const float*)d_in[5];
  const float* Wv = (const float*)d_in[6];
  const float* bv = (const float*)d_in[7];
  const float* Wa = (const float*)d_in[8];
  const float* ba = (const float*)d_in[9];
  const float* Wp = (const float*)d_in[10];
  const float* bp = (const float*)d_in[11];
  float* out = (float*)d_out;

  char* ws = (char*)d_ws;
  bf16* Xb = (bf16*)ws;    ws += (size_t)B_ * S_ * D_ * 2;
  bf16* Wqb = (bf16*)ws;   ws += (size_t)D_ * D_ * 2;
  bf16* Wkb = (bf16*)ws;   ws += (size_t)D_ * D_ * 2;
  bf16* Qb = (bf16*)ws;    ws += (size_t)B_ * S_ * D_ * 2;   // head-major [bh,S,DK]
  bf16* Kbf = (bf16*)ws;   ws += (size_t)B_ * S_ * D_ * 2;   // head-major [bh,S,DK]
  float* score = (float*)ws;  ws += (size_t)B_ * H_ * S_ * 4;
  float* attn = (float*)ws;   ws += (size_t)B_ * H_ * S_ * 4;
  float* xbar = (float*)ws;   ws += (size_t)B_ * H_ * D_ * 4;
  float* pooled = (float*)ws; ws += (size_t)B_ * D_ * 4;
  // part overlays Wqb/Wkb (16 MB, dead after gemm_qk); needs 64*B*H*D*4 = 8.4 MB
  float* part = (float*)Wqb;

  const int nX4 = B_ * S_ * D_ / 4, nW4 = D_ * D_ / 4;
  cvt_all_kernel<<<(nX4 + 2 * nW4) / 256, 256, 0, stream>>>(
      x, Xb, Wq, Wqb, Wk, Wkb, nX4, nW4);

  gemm_qk<<<dim3(D_ / 128, B_ * S_ / 128, 2), 256, 0, stream>>>(
      Xb, Wqb, bq, Qb, Wkb, bk, Kbf);

  hipMemsetAsync(score, 0, (size_t)B_ * H_ * S_ * 4, stream);
  score_kernel<<<dim3(B_ * H_, S_ / 128, S_ / 128), 256, 0, stream>>>(
      Qb, Kbf, Wa, score);

  softmax_kernel<<<B_ * H_, 256, 0, stream>>>(score, xmask, ba, attn);

  xbar_part_kernel<<<dim3(2, 64, B_), 256, 0, stream>>>(x, attn, part);
  xbar_reduce_kernel<<<B_ * H_ * D_ / 256, 256, 0, stream>>>(part, xbar);

  pooled_kernel<<<D_ / 4, 256, 0, stream>>>(xbar, Wv, bv, pooled);
  final_kernel<<<D_ / 4, 256, 0, stream>>>(pooled, Wp, bp, out);
}

// Round 9
// 311.231 us; speedup vs baseline: 1.2959x; 1.1031x over previous
//
#include <hip/hip_runtime.h>
#include <hip/hip_bf16.h>
#include <stdint.h>

#define B_ 2
#define S_ 2048
#define D_ 2048
#define H_ 8
#define DK_ 256
#define SCALE_ 0.0625f
#define NEG_ -1e9f

typedef __hip_bfloat16 bf16;
typedef __attribute__((ext_vector_type(4))) float f32x4;
typedef __attribute__((ext_vector_type(8))) short bf16x8;
typedef unsigned int u32;

__device__ inline void gload_lds16(const void* g, void* l) {
  __builtin_amdgcn_global_load_lds(
      (const __attribute__((address_space(1))) u32*)g,
      (__attribute__((address_space(3))) u32*)l, 16, 0, 0);
}

// ---------------- fused fp32 -> bf16 convert (x, Wq, Wk in one launch) ----------------
__global__ void cvt_all_kernel(const float* __restrict__ x, bf16* __restrict__ xo,
                               const float* __restrict__ wq, bf16* __restrict__ wqo,
                               const float* __restrict__ wk, bf16* __restrict__ wko,
                               int nX4, int nW4) {
  int i = blockIdx.x * 256 + threadIdx.x;
  const float* in; bf16* out; int idx;
  if (i < nX4) { in = x; out = xo; idx = i; }
  else if (i < nX4 + nW4) { in = wq; out = wqo; idx = i - nX4; }
  else { in = wk; out = wko; idx = i - nX4 - nW4; }
  float4 v = ((const float4*)in)[idx];
  ushort4 o;
  o.x = __builtin_bit_cast(unsigned short, __float2bfloat16(v.x));
  o.y = __builtin_bit_cast(unsigned short, __float2bfloat16(v.y));
  o.z = __builtin_bit_cast(unsigned short, __float2bfloat16(v.z));
  o.w = __builtin_bit_cast(unsigned short, __float2bfloat16(v.w));
  ((ushort4*)out)[idx] = o;
}

// ---------------- fused Q/K projection GEMM: 256^2 tile, 8 waves, deep pipeline --------
// C = A[M,K] @ W[N,K]^T + bias, stored bf16 HEAD-MAJOR: C[b,h,s,dk].
// T2: LDS XOR-swizzle (byte ^= (row&7)<<4), pre-swizzled gload source + swizzled ds_read.
// T3/T4: 2-K-step prefetch depth, counted vmcnt(8) (never 0 in main loop), raw s_barrier.
// T5: setprio around MFMA clusters.
__global__ __launch_bounds__(512, 2) void gemm_qk(
    const bf16* __restrict__ A,
    const bf16* __restrict__ W0, const float* __restrict__ b0, bf16* __restrict__ C0,
    const bf16* __restrict__ W1, const float* __restrict__ b1, bf16* __restrict__ C1) {
  const int K = D_;
  const bf16* Bm = blockIdx.z ? W1 : W0;
  const float* bias = blockIdx.z ? b1 : b0;
  bf16* C = blockIdx.z ? C1 : C0;

  __shared__ bf16 As[2][256 * 64];   // 2 x 32KB
  __shared__ bf16 Bs[2][256 * 64];   // 2 x 32KB
  const int tid = threadIdx.x;
  const int lane = tid & 63;
  const int w = tid >> 6;            // 0..7
  const int wr = w >> 2, wc = w & 3; // 2M x 4N wave grid; wave tile 128x64
  const int bn = blockIdx.x, bm = blockIdx.y;

  f32x4 acc[8][4] = {};

  // staging source (pre-swizzled): call c stages rows c*64+(tid>>3), 16B slot tid&7
  const int srow = tid >> 3;               // 0..63
  const int scol8 = ((tid & 7) ^ (srow & 7)) * 8;  // swizzled element offset in row
  const bf16* aSrc = A + (size_t)(bm * 256 + srow) * K + scol8;
  const bf16* bSrc = Bm + (size_t)(bn * 256 + srow) * K + scol8;
  char* aDst = (char*)&As[0][0] + tid * 16;
  char* bDst = (char*)&Bs[0][0] + tid * 16;

  auto STAGE = [&](int buf, int t) {           // 8 vmem instr / wave
    const int kt = t * 64;
#pragma unroll
    for (int c = 0; c < 4; ++c) {
      gload_lds16(aSrc + (size_t)(c * 64) * K + kt, aDst + buf * 32768 + c * 8192);
      gload_lds16(bSrc + (size_t)(c * 64) * K + kt, bDst + buf * 32768 + c * 8192);
    }
  };

  // fragment read addressing (swizzled)
  const int fr = lane & 15, fk = lane >> 4;
  const int swz = (fr & 7) << 4;
  const char* asB = (const char*)&As[0][0];
  const char* bsB = (const char*)&Bs[0][0];
  const int aRow = (wr * 128 + fr) * 128;    // + mi*2048
  const int bRow = (wc * 64 + fr) * 128;     // + ni*2048

  auto READ_A = [&](int buf, int kk, bf16x8* af) {
    const int kb = ((((kk * 4) + fk) << 4) ^ swz) + buf * 32768;
#pragma unroll
    for (int mi = 0; mi < 8; ++mi)
      af[mi] = *(const bf16x8*)(asB + aRow + mi * 2048 + kb);
  };
  auto READ_B = [&](int buf, int kk, bf16x8* bv) {
    const int kb = ((((kk * 4) + fk) << 4) ^ swz) + buf * 32768;
#pragma unroll
    for (int ni = 0; ni < 4; ++ni)
      bv[ni] = *(const bf16x8*)(bsB + bRow + ni * 2048 + kb);
  };
  auto MFMA32 = [&](const bf16x8* af, const bf16x8* bv) {
    __builtin_amdgcn_s_setprio(1);
#pragma unroll
    for (int mi = 0; mi < 8; ++mi)
#pragma unroll
      for (int ni = 0; ni < 4; ++ni)
        acc[mi][ni] = __builtin_amdgcn_mfma_f32_16x16x32_bf16(af[mi], bv[ni], acc[mi][ni], 0, 0, 0);
    __builtin_amdgcn_s_setprio(0);
  };

  // prologue: stage K-steps 0,1 (16 instr); drain step 0 (keep 8 in flight)
  STAGE(0, 0);
  STAGE(1, 1);
  asm volatile("s_waitcnt vmcnt(8)" ::: "memory");
  __builtin_amdgcn_s_barrier();

  const int NT = K / 64;  // 32
  for (int t = 0; t < NT - 2; ++t) {
    const int cur = t & 1;
    {  // kk0 sub-phase
      bf16x8 af[8], bv[4];
      READ_A(cur, 0, af); READ_B(cur, 0, bv);
      MFMA32(af, bv);
    }
    {  // kk1 sub-phase: reads drained, then overwrite-barrier, prefetch t+2, compute
      bf16x8 af[8], bv[4];
      READ_A(cur, 1, af); READ_B(cur, 1, bv);
      asm volatile("s_waitcnt lgkmcnt(0)" ::: "memory");
      __builtin_amdgcn_sched_barrier(0);
      __builtin_amdgcn_s_barrier();          // all waves done reading buf cur
      STAGE(cur, t + 2);                     // overwrite cur with step t+2
      MFMA32(af, bv);
      asm volatile("s_waitcnt vmcnt(8)" ::: "memory");  // step t+1 landed; t+2 in flight
      __builtin_amdgcn_s_barrier();
    }
  }
  {  // t = NT-2: no prefetch; drain fully for last step
    const int cur = (NT - 2) & 1;
    bf16x8 af[8], bv[4];
    READ_A(cur, 0, af); READ_B(cur, 0, bv);
    MFMA32(af, bv);
    READ_A(cur, 1, af); READ_B(cur, 1, bv);
    asm volatile("s_waitcnt lgkmcnt(0)" ::: "memory");
    __builtin_amdgcn_sched_barrier(0);
    MFMA32(af, bv);
    asm volatile("s_waitcnt vmcnt(0)" ::: "memory");
    __builtin_amdgcn_s_barrier();
  }
  {  // t = NT-1
    const int cur = (NT - 1) & 1;
    bf16x8 af[8], bv[4];
    READ_A(cur, 0, af); READ_B(cur, 0, bv);
    MFMA32(af, bv);
    READ_A(cur, 1, af); READ_B(cur, 1, bv);
    MFMA32(af, bv);
  }

  // epilogue: C layout col=lane&15 (per ni), row=(lane>>4)*4+r (per mi); head-major store
#pragma unroll
  for (int ni = 0; ni < 4; ++ni) {
    int col = bn * 256 + wc * 64 + ni * 16 + (lane & 15);
    int h = col >> 8, dk = col & 255;
    float bb = bias[col];
#pragma unroll
    for (int mi = 0; mi < 8; ++mi) {
      int rbase = bm * 256 + wr * 128 + mi * 16 + (lane >> 4) * 4;
#pragma unroll
      for (int r = 0; r < 4; ++r) {
        int row = rbase + r;
        int b = row >> 11, s = row & 2047;
        C[(((size_t)b * H_ + h) * S_ + s) * DK_ + dk] = __float2bfloat16(acc[mi][ni][r] + bb);
      }
    }
  }
}

// ---------------- score kernel v5: m97-style GEMM tile with fused lrelu*Wa epilogue ----
// score[bh,i] += sum_{j in tile} lrelu(q_i.k_j)*Wa[j]; head-major Q/K [bh,S,DK].
// grid (16 bh, 16 bm, 16 bn): linear id % 8 == bh % 8 -> per-head XCD L2 affinity.
__global__ __launch_bounds__(256, 2) void score_kernel(
    const bf16* __restrict__ Qh, const bf16* __restrict__ Kh,
    const float* __restrict__ Wa, float* __restrict__ score) {
  __shared__ bf16 Qs[128 * 64];
  __shared__ bf16 Ks[128 * 64];
  __shared__ float sred[2][128];
  const int tid = threadIdx.x;
  const int lane = tid & 63;
  const int w = tid >> 6;
  const int wr = w >> 1, wc = w & 1;
  const int bh = blockIdx.x, bm = blockIdx.y, bn = blockIdx.z;

  const bf16* Qbase = Qh + (size_t)bh * S_ * DK_;
  const bf16* Kbase = Kh + (size_t)bh * S_ * DK_;

  f32x4 acc[4][4] = {};
  const int l8r = lane >> 3;
  const int l8c = (lane & 7) * 8;

  for (int kt = 0; kt < DK_; kt += 64) {
#pragma unroll
    for (int cc = 0; cc < 4; ++cc) {
      int chunk = w * 4 + cc;                       // 0..15
      int rowa = bm * 128 + chunk * 8 + l8r;
      gload_lds16(Qbase + (size_t)rowa * DK_ + kt + l8c, (char*)Qs + chunk * 1024);
      int rowb = bn * 128 + chunk * 8 + l8r;
      gload_lds16(Kbase + (size_t)rowb * DK_ + kt + l8c, (char*)Ks + chunk * 1024);
    }
    __syncthreads();
#pragma unroll
    for (int kk = 0; kk < 2; ++kk) {
      const int kloc = kk * 32 + (lane >> 4) * 8;
      bf16x8 af[4], bfr[4];
#pragma unroll
      for (int mi = 0; mi < 4; ++mi) {
        int row = wr * 64 + mi * 16 + (lane & 15);
        af[mi] = *(const bf16x8*)&Qs[row * 64 + kloc];
      }
#pragma unroll
      for (int ni = 0; ni < 4; ++ni) {
        int row = wc * 64 + ni * 16 + (lane & 15);
        bfr[ni] = *(const bf16x8*)&Ks[row * 64 + kloc];
      }
#pragma unroll
      for (int mi = 0; mi < 4; ++mi)
#pragma unroll
        for (int ni = 0; ni < 4; ++ni)
          acc[mi][ni] = __builtin_amdgcn_mfma_f32_16x16x32_bf16(af[mi], bfr[ni], acc[mi][ni], 0, 0, 0);
    }
    __syncthreads();
  }
  float wa_v[4];
#pragma unroll
  for (int ni = 0; ni < 4; ++ni)
    wa_v[ni] = Wa[bn * 128 + wc * 64 + ni * 16 + (lane & 15)];
  float psum[4][4] = {};   // [mi][r]
#pragma unroll
  for (int mi = 0; mi < 4; ++mi)
#pragma unroll
    for (int ni = 0; ni < 4; ++ni)
#pragma unroll
      for (int r = 0; r < 4; ++r) {
        float v = acc[mi][ni][r];
        v = (v > 0.f) ? v : 0.1f * v;   // leaky_relu 0.1
        psum[mi][r] += v * wa_v[ni];
      }
#pragma unroll
  for (int mi = 0; mi < 4; ++mi)
#pragma unroll
    for (int r = 0; r < 4; ++r) {
      float v = psum[mi][r];
      v += __shfl_xor(v, 1); v += __shfl_xor(v, 2);
      v += __shfl_xor(v, 4); v += __shfl_xor(v, 8);
      if ((lane & 15) == 0) {
        int lrow = wr * 64 + mi * 16 + ((lane >> 4) * 4) + r;  // 0..127
        sred[wc][lrow] = v;
      }
    }
  __syncthreads();
  if (tid < 128)
    atomicAdd(&score[(size_t)bh * S_ + bm * 128 + tid], sred[0][tid] + sred[1][tid]);
}

// ---------------- masked scaled softmax over tokens ----------------
__global__ __launch_bounds__(256) void softmax_kernel(
    const float* __restrict__ score, const int* __restrict__ xmask,
    const float* __restrict__ ba, float* __restrict__ attn) {
  const int bh = blockIdx.x, tid = threadIdx.x;
  const int lane = tid & 63, w = tid >> 6;
  __shared__ float redm[4], reds[4];
  const float ba0 = ba[0];
  float loc[8];
  float mx = -3.4e38f;
#pragma unroll
  for (int t = 0; t < 8; ++t) {
    int i = t * 256 + tid;
    float s = SCALE_ * (score[(size_t)bh * S_ + i] + ba0);
    if (xmask[i] != 0) s = NEG_;
    loc[t] = s;
    mx = fmaxf(mx, s);
  }
  for (int m = 1; m < 64; m <<= 1) mx = fmaxf(mx, __shfl_xor(mx, m));
  if (lane == 0) redm[w] = mx;
  __syncthreads();
  mx = fmaxf(fmaxf(redm[0], redm[1]), fmaxf(redm[2], redm[3]));
  float sum = 0.f;
#pragma unroll
  for (int t = 0; t < 8; ++t) {
    loc[t] = expf(loc[t] - mx);
    sum += loc[t];
  }
  for (int m = 1; m < 64; m <<= 1) sum += __shfl_xor(sum, m);
  if (lane == 0) reds[w] = sum;
  __syncthreads();
  sum = reds[0] + reds[1] + reds[2] + reds[3];
  const float inv = 1.f / sum;
#pragma unroll
  for (int t = 0; t < 8; ++t) attn[(size_t)bh * S_ + t * 256 + tid] = loc[t] * inv;
}

// ---------------- xbar partials: part[sblk][b][h][c] = sum_{s in blk} attn*x ----------------
__global__ __launch_bounds__(256) void xbar_part_kernel(
    const float* __restrict__ x, const float* __restrict__ attn, float* __restrict__ part) {
  const int cblk = blockIdx.x, sblk = blockIdx.y, b = blockIdx.z;
  const int tid = threadIdx.x;
  const int c = cblk * 1024 + tid * 4;
  __shared__ float at_s[8][32];
  for (int i = tid; i < 8 * 32; i += 256) {
    int h = i >> 5, s = i & 31;
    at_s[h][s] = attn[((size_t)b * H_ + h) * S_ + sblk * 32 + s];
  }
  __syncthreads();
  float acc[8][4] = {};
  const float* xp = x + ((size_t)b * S_ + sblk * 32) * D_ + c;
#pragma unroll 8
  for (int s = 0; s < 32; ++s) {
    float4 xv = *(const float4*)(xp + (size_t)s * D_);
#pragma unroll
    for (int h = 0; h < 8; ++h) {
      float a = at_s[h][s];
      acc[h][0] += a * xv.x; acc[h][1] += a * xv.y;
      acc[h][2] += a * xv.z; acc[h][3] += a * xv.w;
    }
  }
  float* pp = part + (((size_t)sblk * B_ + b) * H_) * D_ + c;
#pragma unroll
  for (int h = 0; h < 8; ++h)
    *(float4*)(pp + (size_t)h * D_) = *(const float4*)&acc[h][0];
}

// ---------------- xbar[b][h][c] = sum_sblk part[sblk][b][h][c] ----------------
__global__ __launch_bounds__(256) void xbar_reduce_kernel(
    const float* __restrict__ part, float* __restrict__ xbar) {
  const int idx = blockIdx.x * 256 + threadIdx.x;  // [0, B*H*D)
  float s = 0.f;
#pragma unroll 8
  for (int sb = 0; sb < 64; ++sb)
    s += part[(size_t)sb * (B_ * H_ * D_) + idx];
  xbar[idx] = s;
}

// ---------------- pooled[b,dv] = xbar[b,h(dv),:].Wv[dv,:] + bv[dv] ----------------
__global__ __launch_bounds__(256) void pooled_kernel(
    const float* __restrict__ xbar, const float* __restrict__ Wv,
    const float* __restrict__ bv, float* __restrict__ pooled) {
  const int lane = threadIdx.x & 63;
  const int dv = blockIdx.x * 4 + (threadIdx.x >> 6);
  const int h = dv >> 8;  // dv / DK_
  const float* wrow = Wv + (size_t)dv * D_;
  const float* x0 = xbar + (size_t)h * D_;
  const float* x1 = xbar + (size_t)(H_ + h) * D_;
  float a0 = 0.f, a1 = 0.f;
  for (int c = lane; c < D_; c += 64) {
    float wv = wrow[c];
    a0 += wv * x0[c];
    a1 += wv * x1[c];
  }
  for (int m = 1; m < 64; m <<= 1) { a0 += __shfl_xor(a0, m); a1 += __shfl_xor(a1, m); }
  if (lane == 0) {
    float bb = bv[dv];
    pooled[dv] = a0 + bb;
    pooled[D_ + dv] = a1 + bb;
  }
}

// ---------------- out[b,n] = tanh(pooled[b,:].Wp[n,:] + bp[n]) ----------------
__global__ __launch_bounds__(256) void final_kernel(
    const float* __restrict__ pooled, const float* __restrict__ Wp,
    const float* __restrict__ bp, float* __restrict__ out) {
  const int lane = threadIdx.x & 63;
  const int n = blockIdx.x * 4 + (threadIdx.x >> 6);
  const float* wrow = Wp + (size_t)n * D_;
  float a0 = 0.f, a1 = 0.f;
  for (int c = lane; c < D_; c += 64) {
    float wv = wrow[c];
    a0 += wv * pooled[c];
    a1 += wv * pooled[D_ + c];
  }
  for (int m = 1; m < 64; m <<= 1) { a0 += __shfl_xor(a0, m); a1 += __shfl_xor(a1, m); }
  if (lane == 0) {
    float bb = bp[n];
    out[n] = tanhf(a0 + bb);
    out[D_ + n] = tanhf(a1 + bb);
  }
}

extern "C" void kernel_launch(void* const* d_in, const int* in_sizes, int n_in,
                              void* d_out, int out_size, void* d_ws, size_t ws_size,
                              hipStream_t stream) {
  const float* x = (const float*)d_in[0];
  const int* xmask = (const int*)d_in[1];
  const float* Wq = (const float*)d_in[2];
  const float* bq = (const float*)d_in[3];
  const float* Wk = (const float*)d_in[4];
  const float* bk = (const float*)d_in[5];
  const float* Wv = (const float*)d_in[6];
  const float* bv = (const float*)d_in[7];
  const float* Wa = (const float*)d_in[8];
  const float* ba = (const float*)d_in[9];
  const float* Wp = (const float*)d_in[10];
  const float* bp = (const float*)d_in[11];
  float* out = (float*)d_out;

  char* ws = (char*)d_ws;
  bf16* Xb = (bf16*)ws;    ws += (size_t)B_ * S_ * D_ * 2;
  bf16* Wqb = (bf16*)ws;   ws += (size_t)D_ * D_ * 2;
  bf16* Wkb = (bf16*)ws;   ws += (size_t)D_ * D_ * 2;
  bf16* Qb = (bf16*)ws;    ws += (size_t)B_ * S_ * D_ * 2;   // head-major [bh,S,DK]
  bf16* Kbf = (bf16*)ws;   ws += (size_t)B_ * S_ * D_ * 2;   // head-major [bh,S,DK]
  float* score = (float*)ws;  ws += (size_t)B_ * H_ * S_ * 4;
  float* attn = (float*)ws;   ws += (size_t)B_ * H_ * S_ * 4;
  float* xbar = (float*)ws;   ws += (size_t)B_ * H_ * D_ * 4;
  float* pooled = (float*)ws; ws += (size_t)B_ * D_ * 4;
  // part overlays Wqb/Wkb (16 MB, dead after gemm_qk); needs 64*B*H*D*4 = 8.4 MB
  float* part = (float*)Wqb;

  const int nX4 = B_ * S_ * D_ / 4, nW4 = D_ * D_ / 4;
  cvt_all_kernel<<<(nX4 + 2 * nW4) / 256, 256, 0, stream>>>(
      x, Xb, Wq, Wqb, Wk, Wkb, nX4, nW4);

  gemm_qk<<<dim3(D_ / 256, B_ * S_ / 256, 2), 512, 0, stream>>>(
      Xb, Wqb, bq, Qb, Wkb, bk, Kbf);

  hipMemsetAsync(score, 0, (size_t)B_ * H_ * S_ * 4, stream);
  score_kernel<<<dim3(B_ * H_, S_ / 128, S_ / 128), 256, 0, stream>>>(
      Qb, Kbf, Wa, score);

  softmax_kernel<<<B_ * H_, 256, 0, stream>>>(score, xmask, ba, attn);

  xbar_part_kernel<<<dim3(2, 64, B_), 256, 0, stream>>>(x, attn, part);
  xbar_reduce_kernel<<<B_ * H_ * D_ / 256, 256, 0, stream>>>(part, xbar);

  pooled_kernel<<<D_ / 4, 256, 0, stream>>>(xbar, Wv, bv, pooled);
  final_kernel<<<D_ / 4, 256, 0, stream>>>(pooled, Wp, bp, out);
}